// Round 9
// baseline (153.889 us; speedup 1.0000x reference)
//
#include <hip/hip_runtime.h>

#define BB 8
#define CC 128

typedef _Float16 f16x4 __attribute__((ext_vector_type(4)));
typedef float f32x4 __attribute__((ext_vector_type(4)));

// Bilinear sample from a zero-border padded LDS plane.
// pl is [H+3][stride] with interior pixel (r,c) at pl[(r+1)*stride + (c+1)],
// border rows/cols are 0. Coords clamped to [-1, W]; out-of-range taps read 0.
__device__ __forceinline__ float sample_pad(const float* __restrict__ pl, int stride,
                                            float WF, float ix, float iy) {
  ix = fminf(fmaxf(ix, -1.0f), WF);
  iy = fminf(fmaxf(iy, -1.0f), WF);
  float x0f = floorf(ix), y0f = floorf(iy);
  float wx = ix - x0f, wy = iy - y0f;
  int xi = (int)x0f + 1, yi = (int)y0f + 1;
  const float* p0 = pl + yi * stride + xi;
  float v00 = p0[0], v01 = p0[1], v10 = p0[stride], v11 = p0[stride + 1];
  return (1.0f - wy) * ((1.0f - wx) * v00 + wx * v01) +
         wy * ((1.0f - wx) * v10 + wx * v11);
}

// Factorized box mask: validity of tap(i,j) = X_i * Y_j, so bilinear sum = mx*my.
__device__ __forceinline__ float box_mask(float bix, float biy, float WM1) {
  float bx0 = floorf(bix), by0 = floorf(biy);
  float bwx = bix - bx0, bwy = biy - by0;
  float mx = (((bx0 >= 0.0f) && (bx0 <= WM1)) ? (1.0f - bwx) : 0.0f) +
             (((bx0 >= -1.0f) && (bx0 <= WM1 - 1.0f)) ? bwx : 0.0f);
  float my = (((by0 >= 0.0f) && (by0 <= WM1)) ? (1.0f - bwy) : 0.0f) +
             (((by0 >= -1.0f) && (by0 <= WM1 - 1.0f)) ? bwy : 0.0f);
  return mx * my;
}

// ---------------- fused inLay: combine -> padded LDS + sample + box mask ----------
__global__ __launch_bounds__(256) void inlay_sample_kernel(
    const float* __restrict__ x, const float* __restrict__ lin,
    const float* __restrict__ geo, const float* __restrict__ box,
    const float* __restrict__ db, float* __restrict__ out,
    float* __restrict__ head) {
  const int H = 64, W = 64, HW = 4096;
  __shared__ float cp[67 * 68];
  int bc = blockIdx.x;
  int c = bc & (CC - 1);
  int b = bc >> 7;
  int tid = threadIdx.x;
  if (bc == 0 && tid < 80) head[tid] = db[tid % 10];  // bias init for atomic dense
  const float* xb = x + (size_t)b * 3 * HW;

  float w0 = lin[c * 3 + 0], w1 = lin[c * 3 + 1], w2 = lin[c * 3 + 2];

  if (tid < 68) {
    cp[tid] = 0.0f; cp[65 * 68 + tid] = 0.0f; cp[66 * 68 + tid] = 0.0f;
  } else if (tid < 132) {
    int r = tid - 67;
    cp[r * 68 + 0] = 0.0f; cp[r * 68 + 65] = 0.0f; cp[r * 68 + 66] = 0.0f;
  }

#pragma unroll
  for (int k = 0; k < 4; ++k) {
    int i4 = tid + k * 256;
    int base = i4 * 4;
    float4 f0 = *reinterpret_cast<const float4*>(&xb[base]);
    float4 f1 = *reinterpret_cast<const float4*>(&xb[HW + base]);
    float4 f2 = *reinterpret_cast<const float4*>(&xb[2 * HW + base]);
    int h = i4 >> 4, w = (i4 & 15) * 4;
    float* d = &cp[(h + 1) * 68 + w + 1];
    d[0] = w0 * f0.x + w1 * f1.x + w2 * f2.x;
    d[1] = w0 * f0.y + w1 * f1.y + w2 * f2.y;
    d[2] = w0 * f0.z + w1 * f1.z + w2 * f2.z;
    d[3] = w0 * f0.w + w1 * f1.w + w2 * f2.w;
  }
  __syncthreads();

  const float* g = geo + c * 6;
  const float* bx = box + c * 6;
  float g0 = g[0], g1 = g[1], g2 = g[2], g3 = g[3], g4 = g[4], g5 = g[5];
  float b0 = bx[0], b1 = bx[1], b2 = bx[2], b3 = bx[3], b4 = bx[4], b5 = bx[5];
  float* o = out + ((size_t)b * CC + c) * HW;

#pragma unroll
  for (int k = 0; k < 16; ++k) {
    int px = tid + k * 256;
    int h = px >> 6, w = px & 63;
    float xs = (2.0f * w + 1.0f) / W - 1.0f;
    float ys = (2.0f * h + 1.0f) / H - 1.0f;
    float ix = ((g0 * xs + g1 * ys + g2 + 1.0f) * W - 1.0f) * 0.5f;
    float iy = ((g3 * xs + g4 * ys + g5 + 1.0f) * H - 1.0f) * 0.5f;
    float samp = sample_pad(cp, 68, 64.0f, ix, iy);
    float bix = ((b0 * xs + b1 * ys + b2 + 1.0f) * W - 1.0f) * 0.5f;
    float biy = ((b3 * xs + b4 * ys + b5 + 1.0f) * H - 1.0f) * 0.5f;
    o[px] = samp * box_mask(bix, biy, 63.0f);
  }
}

// ---------------- layer-0 GEMM via f16 MFMA: 64x64 tile, single-stage LDS ----------
// Layouts verified in rounds 6/7:
//   A frag: lane l holds A[row=l&15][k=16s+4*(l>>4)+j]   (f16x4, one ds_read_b64)
//   B frag: lane l holds B[k=16s+4*(l>>4)+j][col=l&15]
//   D:      lane l holds D[row=4*(l>>4)+i][col=l&15]
__global__ __launch_bounds__(256) void gemm64_mfma_kernel(
    const float* __restrict__ lin, const float* __restrict__ x,
    float* __restrict__ y) {
  const int Ci = 128, HW = 4096;
  __shared__ unsigned int A_lds[64 * 66];  // [row][kp] kp = k/2, stride 66 (pad)
  __shared__ unsigned int B_lds[64 * 66];  // [col][kp]
  int b = blockIdx.z;
  int row0 = blockIdx.y * 64, col0 = blockIdx.x * 64;
  const float* xb = x + (size_t)b * Ci * HW;
  float* yb = y + (size_t)b * CC * HW;
  int tid = threadIdx.x;

  // stage A: thread t -> row = t>>2, k-chunk (t&3)*32 (16 packed words)
  {
    int row = tid >> 2, kc = (tid & 3) * 32;
    const float* ap = &lin[(row0 + row) * Ci + kc];
    unsigned int* dst = &A_lds[row * 66 + (kc >> 1)];
#pragma unroll
    for (int i = 0; i < 8; ++i) {
      float4 v = *reinterpret_cast<const float4*>(ap + i * 4);
      union { _Float16 h[2]; unsigned int u; } p0, p1;
      p0.h[0] = (_Float16)v.x; p0.h[1] = (_Float16)v.y;
      p1.h[0] = (_Float16)v.z; p1.h[1] = (_Float16)v.w;
      dst[i * 2] = p0.u; dst[i * 2 + 1] = p1.u;
    }
  }
  // stage B (transpose): thread t -> kp = t>>2 (rows k=2kp,2kp+1), cols (t&3)*16..+16
  {
    int kp = tid >> 2, cg = (tid & 3) * 16;
    const float* b0p = &xb[(size_t)(2 * kp) * HW + col0 + cg];
    const float* b1p = &xb[(size_t)(2 * kp + 1) * HW + col0 + cg];
#pragma unroll
    for (int q = 0; q < 4; ++q) {
      float4 v0 = *reinterpret_cast<const float4*>(b0p + q * 4);
      float4 v1 = *reinterpret_cast<const float4*>(b1p + q * 4);
      float e0[4] = {v0.x, v0.y, v0.z, v0.w};
      float e1[4] = {v1.x, v1.y, v1.z, v1.w};
#pragma unroll
      for (int c = 0; c < 4; ++c) {
        union { _Float16 h[2]; unsigned int u; } p;
        p.h[0] = (_Float16)e0[c]; p.h[1] = (_Float16)e1[c];
        B_lds[(cg + q * 4 + c) * 66 + kp] = p.u;
      }
    }
  }
  __syncthreads();

  int w = tid >> 6, l = tid & 63;
  int lr = l & 15, lq = l >> 4;
  f32x4 acc0 = {0.f, 0.f, 0.f, 0.f};
  f32x4 acc1 = acc0, acc2 = acc0, acc3 = acc0;
  const unsigned int* arow = &A_lds[(w * 16 + lr) * 66 + 2 * lq];
  const unsigned int* bcol = &B_lds[lr * 66 + 2 * lq];
#pragma unroll
  for (int s = 0; s < 8; ++s) {
    f16x4 af = *reinterpret_cast<const f16x4*>(arow + s * 8);
    f16x4 b0 = *reinterpret_cast<const f16x4*>(bcol + 0 * 16 * 66 + s * 8);
    f16x4 b1 = *reinterpret_cast<const f16x4*>(bcol + 1 * 16 * 66 + s * 8);
    f16x4 b2 = *reinterpret_cast<const f16x4*>(bcol + 2 * 16 * 66 + s * 8);
    f16x4 b3 = *reinterpret_cast<const f16x4*>(bcol + 3 * 16 * 66 + s * 8);
    acc0 = __builtin_amdgcn_mfma_f32_16x16x16f16(af, b0, acc0, 0, 0, 0);
    acc1 = __builtin_amdgcn_mfma_f32_16x16x16f16(af, b1, acc1, 0, 0, 0);
    acc2 = __builtin_amdgcn_mfma_f32_16x16x16f16(af, b2, acc2, 0, 0, 0);
    acc3 = __builtin_amdgcn_mfma_f32_16x16x16f16(af, b3, acc3, 0, 0, 0);
  }
#pragma unroll
  for (int i = 0; i < 4; ++i) {
    float* yr = yb + (size_t)(row0 + w * 16 + lq * 4 + i) * HW + col0 + lr;
    yr[0]  = acc0[i];
    yr[16] = acc1[i];
    yr[32] = acc2[i];
    yr[48] = acc3[i];
  }
}

// ---------------- fused sample(64x64) + MaxPool2d_G -> 32x32, 256 threads ---------
__global__ __launch_bounds__(256) void sampmax_kernel(
    const float* __restrict__ y, const float* __restrict__ geo,
    const float* __restrict__ box, float* __restrict__ out) {
  __shared__ __align__(16) float sp[64 * 68];     // sampled plane
  __shared__ __align__(16) float arena[67 * 68];  // pl padded (ph0-1) then cb (ph2-3)
  __shared__ float wv[4];
  __shared__ int wi[4];
  __shared__ int am_s;
  float* pl = arena;
  float* cb = arena;

  int bc = blockIdx.x;
  int c = bc & (CC - 1);
  int tid = threadIdx.x;

  if (tid < 68) {
    pl[tid] = 0.0f; pl[65 * 68 + tid] = 0.0f; pl[66 * 68 + tid] = 0.0f;
  } else if (tid < 132) {
    int r = tid - 67;
    pl[r * 68 + 0] = 0.0f; pl[r * 68 + 65] = 0.0f; pl[r * 68 + 66] = 0.0f;
  }
  {
    const float* plane = y + (size_t)bc * 4096;
#pragma unroll
    for (int k = 0; k < 4; ++k) {
      int i4 = tid + k * 256;
      float4 f = *reinterpret_cast<const float4*>(&plane[i4 * 4]);
      int h = i4 >> 4, w = (i4 & 15) * 4;
      float* d = &pl[(h + 1) * 68 + w + 1];
      d[0] = f.x; d[1] = f.y; d[2] = f.z; d[3] = f.w;
    }
  }
  __syncthreads();

  {
    const float* g = geo + c * 6;
    const float* bx = box + c * 6;
    float g0 = g[0], g1 = g[1], g2 = g[2], g3 = g[3], g4 = g[4], g5 = g[5];
    float b0 = bx[0], b1 = bx[1], b2 = bx[2], b3 = bx[3], b4 = bx[4], b5 = bx[5];
#pragma unroll
    for (int k = 0; k < 16; ++k) {
      int px = tid + k * 256;
      int h = px >> 6, w = px & 63;
      float xs = (2.0f * w + 1.0f) / 64.0f - 1.0f;
      float ys = (2.0f * h + 1.0f) / 64.0f - 1.0f;
      float ix = ((g0 * xs + g1 * ys + g2 + 1.0f) * 64.0f - 1.0f) * 0.5f;
      float iy = ((g3 * xs + g4 * ys + g5 + 1.0f) * 64.0f - 1.0f) * 0.5f;
      float samp = sample_pad(pl, 68, 64.0f, ix, iy);
      float bix = ((b0 * xs + b1 * ys + b2 + 1.0f) * 64.0f - 1.0f) * 0.5f;
      float biy = ((b3 * xs + b4 * ys + b5 + 1.0f) * 64.0f - 1.0f) * 0.5f;
      sp[h * 68 + w] = samp * box_mask(bix, biy, 63.0f);
    }
  }
  __syncthreads();

  // Phase 2: vertical 32-row sliding box sums -> cb
  {
    int strip = tid >> 4, w4 = (tid & 15) * 4;
    int h0 = strip * 4;
    float4 a = make_float4(0.f, 0.f, 0.f, 0.f);
    float4 keep0 = a, keep1 = a, keep2 = a;
#pragma unroll
    for (int j = 0; j < 32; ++j) {
      int r = h0 + j - 16;
      bool valid = (r >= 0) && (r < 64);
      int rc = valid ? r : 0;
      float4 f = *reinterpret_cast<const float4*>(&sp[rc * 68 + w4]);
      f.x = valid ? f.x : 0.0f; f.y = valid ? f.y : 0.0f;
      f.z = valid ? f.z : 0.0f; f.w = valid ? f.w : 0.0f;
      if (j == 0) keep0 = f;
      if (j == 1) keep1 = f;
      if (j == 2) keep2 = f;
      a.x += f.x; a.y += f.y; a.z += f.z; a.w += f.w;
    }
    *reinterpret_cast<float4*>(&cb[(h0 + 0) * 68 + w4]) = a;
#pragma unroll
    for (int j = 32; j < 35; ++j) {
      int r = h0 + j - 16;
      bool valid = (r < 64);
      int rc = valid ? r : 0;
      float4 f = *reinterpret_cast<const float4*>(&sp[rc * 68 + w4]);
      f.x = valid ? f.x : 0.0f; f.y = valid ? f.y : 0.0f;
      f.z = valid ? f.z : 0.0f; f.w = valid ? f.w : 0.0f;
      float4 kp = (j == 32) ? keep0 : ((j == 33) ? keep1 : keep2);
      a.x += f.x - kp.x; a.y += f.y - kp.y; a.z += f.z - kp.z; a.w += f.w - kp.w;
      *reinterpret_cast<float4*>(&cb[(h0 + j - 31) * 68 + w4]) = a;
    }
  }
  __syncthreads();

  // Phase 3: horizontal 32-col sliding box sums + argmax
  float best = -3.402823466e+38f;
  int bidx = 0x7fffffff;
#pragma unroll
  for (int hh = 0; hh < 4; ++hh) {
    int h = (tid >> 4) + hh * 16;
    int w4 = (tid & 15) * 4;
    float s0 = 0.f, k0 = 0.f, k1 = 0.f, k2 = 0.f;
#pragma unroll
    for (int q = 0; q < 8; ++q) {
      int u0 = w4 - 16 + 4 * q;
      bool ok = (u0 >= 0) && (u0 <= 60);
      int uc = ok ? u0 : 0;
      float4 f = *reinterpret_cast<const float4*>(&cb[h * 68 + uc]);
      f.x = ok ? f.x : 0.0f; f.y = ok ? f.y : 0.0f;
      f.z = ok ? f.z : 0.0f; f.w = ok ? f.w : 0.0f;
      if (q == 0) { k0 = f.x; k1 = f.y; k2 = f.z; }
      s0 += f.x; s0 += f.y; s0 += f.z; s0 += f.w;
    }
    float ftx = 0.f, fty = 0.f, ftz = 0.f;
    {
      int u0 = w4 + 16;
      bool ok = (u0 <= 60);
      int uc = ok ? u0 : 0;
      float4 f = *reinterpret_cast<const float4*>(&cb[h * 68 + uc]);
      ftx = ok ? f.x : 0.0f; fty = ok ? f.y : 0.0f; ftz = ok ? f.z : 0.0f;
    }
    float s1 = s0 - k0 + ftx;
    float s2 = s1 - k1 + fty;
    float s3 = s2 - k2 + ftz;
    float sv[4] = {s0, s1, s2, s3};
#pragma unroll
    for (int d = 0; d < 4; ++d) {
      int i = (h << 6) + w4 + d;
      if (sv[d] > best) { best = sv[d]; bidx = i; }
    }
  }
#pragma unroll
  for (int off = 32; off > 0; off >>= 1) {
    float v2 = __shfl_down(best, off);
    int i2 = __shfl_down(bidx, off);
    if (v2 > best || (v2 == best && i2 < bidx)) { best = v2; bidx = i2; }
  }
  if ((tid & 63) == 0) { wv[tid >> 6] = best; wi[tid >> 6] = bidx; }
  __syncthreads();
  if (tid == 0) {
    float bv = wv[0]; int bi = wi[0];
#pragma unroll
    for (int k = 1; k < 4; ++k)
      if (wv[k] > bv || (wv[k] == bv && wi[k] < bi)) { bv = wv[k]; bi = wi[k]; }
    am_s = bi;
  }
  __syncthreads();

  int am = am_s;
  int r = am >> 6, cx = am & 63;
  float* o = out + (size_t)bc * 1024;
#pragma unroll
  for (int k = 0; k < 4; ++k) {
    int idx = tid + k * 256;
    int oi = idx >> 5, oj = idx & 31;
    int rr = r + oi - 16, cj = cx + oj - 16;
    bool v = (rr >= 0) && (rr < 64) && (cj >= 0) && (cj < 64);
    int rrc = v ? rr : 0, cjc = v ? cj : 0;
    o[idx] = v ? sp[rrc * 68 + cjc] : 0.0f;
  }
}

// ======= fused 32x32 layer: f16-MFMA GEMM (16ch x 1024px) + in-LDS sample =========
// Block: 16 channels x full plane; grid (8 ch-groups, 8 batches) = 64 blocks, 512 thr
// = 8 waves, each owning 8 col-tiles (8x8=64 tiles = 1024 px; round-8 bug was 16/wave).
// K staged in 4 chunks of 32 (Bw [col=1024][kp=16] words, stride 18: even for b64
// alignment, 18*lr mod 32 distinct -> conflict-free). After GEMM, accs are written
// to padded 35x36 planes in LDS (aliasing Bw) and sampled in-kernel.
template <bool POOL>
__global__ __launch_bounds__(512) void fusedgs32_kernel(
    const float* __restrict__ lin, const float* __restrict__ x,
    const float* __restrict__ geo, const float* __restrict__ box,
    float* __restrict__ out, const float* __restrict__ dw,
    float* __restrict__ head) {
  __shared__ __align__(16) float arena[20160];      // B words (18432) / planes (16*1260)
  __shared__ __align__(16) unsigned int A_lds[16 * 66];
  __shared__ float wred[16];
  unsigned int* Bw = reinterpret_cast<unsigned int*>(arena);
  float* planes = arena;

  int c0 = blockIdx.x * 16;
  int b = blockIdx.y;
  int tid = threadIdx.x;
  const float* xb = x + (size_t)b * 128 * 1024;

  // stage A: 16 ch x 128 k, k-pair packed. threads 0..255.
  if (tid < 256) {
    int row = tid >> 4, kg = tid & 15;  // kg: 8 floats = 4 words
    const float* ap = &lin[(c0 + row) * 128 + kg * 8];
    float4 v0 = *reinterpret_cast<const float4*>(ap);
    float4 v1 = *reinterpret_cast<const float4*>(ap + 4);
    unsigned int* dst = &A_lds[row * 66 + kg * 4];
    union { _Float16 h[2]; unsigned int u; } p;
    p.h[0] = (_Float16)v0.x; p.h[1] = (_Float16)v0.y; dst[0] = p.u;
    p.h[0] = (_Float16)v0.z; p.h[1] = (_Float16)v0.w; dst[1] = p.u;
    p.h[0] = (_Float16)v1.x; p.h[1] = (_Float16)v1.y; dst[2] = p.u;
    p.h[0] = (_Float16)v1.z; p.h[1] = (_Float16)v1.w; dst[3] = p.u;
  }

  int w = tid >> 6, l = tid & 63;  // w: 0..7 (8 waves)
  int lr = l & 15, lq = l >> 4;
  f32x4 acc[8];
#pragma unroll
  for (int j = 0; j < 8; ++j) acc[j] = (f32x4){0.f, 0.f, 0.f, 0.f};

  const unsigned int* arow = &A_lds[lr * 66 + 2 * lq];

  for (int kc = 0; kc < 4; ++kc) {
    if (kc) __syncthreads();  // previous chunk's frag reads complete
    // stage B chunk: k in [kc*32, kc*32+32) -> Bw[col*18 + kp], kp = (k - kc*32)/2
    {
      int kpl = tid >> 5;        // 0..15
      int cg = tid & 31;
      const float* r0 = xb + (size_t)(kc * 32 + 2 * kpl) * 1024;
      const float* r1 = r0 + 1024;
#pragma unroll
      for (int q = 0; q < 8; ++q) {
        int col = q * 128 + cg * 4;
        float4 v0 = *reinterpret_cast<const float4*>(r0 + col);
        float4 v1 = *reinterpret_cast<const float4*>(r1 + col);
        float e0[4] = {v0.x, v0.y, v0.z, v0.w};
        float e1[4] = {v1.x, v1.y, v1.z, v1.w};
#pragma unroll
        for (int e = 0; e < 4; ++e) {
          union { _Float16 h[2]; unsigned int u; } p;
          p.h[0] = (_Float16)e0[e]; p.h[1] = (_Float16)e1[e];
          Bw[(col + e) * 18 + kpl] = p.u;
        }
      }
    }
    __syncthreads();
    // MFMA: wave w covers col-tiles w*8..w*8+7 (cols [w*128, w*128+128)); 2 k-steps/chunk
#pragma unroll
    for (int s = 0; s < 2; ++s) {
      f16x4 af = *reinterpret_cast<const f16x4*>(arow + kc * 16 + s * 8);
#pragma unroll
      for (int j = 0; j < 8; ++j) {
        int colbase = (w * 8 + j) * 16 + lr;
        f16x4 bf = *reinterpret_cast<const f16x4*>(&Bw[colbase * 18 + s * 8 + 2 * lq]);
        acc[j] = __builtin_amdgcn_mfma_f32_16x16x16f16(af, bf, acc[j], 0, 0, 0);
      }
    }
  }
  __syncthreads();  // all frag reads done; B region free

  // zero entire planes region (16 x 1260), then write accs into interiors
  for (int i = tid; i < 20160; i += 512) planes[i] = 0.0f;
  __syncthreads();
  // D layout: lane holds D[row=4*lq+i][col] -> ch = 4*lq+i, px = (w*8+j)*16 + lr
#pragma unroll
  for (int j = 0; j < 8; ++j) {
    int px = (w * 8 + j) * 16 + lr;
    int h = px >> 5, wc = px & 31;
    float* base = &planes[(h + 1) * 36 + wc + 1];
#pragma unroll
    for (int i = 0; i < 4; ++i) {
      base[(4 * lq + i) * 1260] = acc[j][i];
    }
  }
  __syncthreads();

  // sample: thread group (tid>>5) owns channel ch; 32 px/thread (row k, col lane32)
  {
    int ch = tid >> 5, lane32 = tid & 31;
    int c = c0 + ch;
    const float* g = geo + c * 6;
    const float* bp = box + c * 6;
    float g0 = g[0], g1 = g[1], g2 = g[2], g3 = g[3], g4 = g[4], g5 = g[5];
    float b0 = bp[0], b1 = bp[1], b2 = bp[2], b3 = bp[3], b4 = bp[4], b5 = bp[5];
    const float* pl = &planes[ch * 1260];
    float* o = out + ((size_t)b * CC + c) * 1024;
    float psum = 0.f;
    float xs = (2.0f * lane32 + 1.0f) / 32.0f - 1.0f;
#pragma unroll
    for (int k = 0; k < 32; ++k) {
      float ys = (2.0f * k + 1.0f) / 32.0f - 1.0f;
      float ix = ((g0 * xs + g1 * ys + g2 + 1.0f) * 32.0f - 1.0f) * 0.5f;
      float iy = ((g3 * xs + g4 * ys + g5 + 1.0f) * 32.0f - 1.0f) * 0.5f;
      float samp = sample_pad(pl, 36, 32.0f, ix, iy);
      float bix = ((b0 * xs + b1 * ys + b2 + 1.0f) * 32.0f - 1.0f) * 0.5f;
      float biy = ((b3 * xs + b4 * ys + b5 + 1.0f) * 32.0f - 1.0f) * 0.5f;
      float res = samp * box_mask(bix, biy, 31.0f);
      o[k * 32 + lane32] = res;
      if (POOL) psum += res;
    }
    if (POOL) {
#pragma unroll
      for (int m = 16; m >= 1; m >>= 1) psum += __shfl_xor(psum, m);
      if (lane32 == 0) wred[ch] = psum;
    }
  }
  if (POOL) {
    __syncthreads();
    if (tid < 10) {
      float s = 0.f;
#pragma unroll
      for (int ch = 0; ch < 16; ++ch)
        s += wred[ch] * (1.0f / 1024.0f) * dw[tid * 128 + c0 + ch];
      atomicAdd(&head[b * 10 + tid], s);
    }
  }
}

extern "C" void kernel_launch(void* const* d_in, const int* in_sizes, int n_in,
                              void* d_out, int out_size, void* d_ws, size_t ws_size,
                              hipStream_t stream) {
  const float* x     = (const float*)d_in[0];   // [8,3,64,64]
  const float* geo0  = (const float*)d_in[1];   // [128,2,3]
  const float* lin0  = (const float*)d_in[2];   // [128,3]
  const float* box0  = (const float*)d_in[3];   // [128,2,3]
  const float* geos  = (const float*)d_in[4];   // [3,128,2,3]
  const float* lins  = (const float*)d_in[5];   // [3,128,128]
  const float* boxes = (const float*)d_in[6];   // [3,128,2,3]
  const float* dw    = (const float*)d_in[7];   // [10,128]
  const float* db    = (const float*)d_in[8];   // [10]

  float* out  = (float*)d_out;      // [8,10] then feat [8,128,32,32]
  float* feat = out + 80;
  float* ws   = (float*)d_ws;
  float* ws0  = ws;                 // 16 MB regions
  float* ws1  = ws + 4194304;

  // inLay: fused combine(Ci=3) + sample -> ws1; also writes head bias
  inlay_sample_kernel<<<dim3(BB * CC), 256, 0, stream>>>(x, lin0, geo0, box0, db, ws1, out);
  // layer 0: f16-MFMA GEMM (64x64 tiles) -> fused sample+maxpool -> 32x32
  gemm64_mfma_kernel<<<dim3(64, 2, BB), 256, 0, stream>>>(lins, ws1, ws0);
  sampmax_kernel<<<dim3(BB * CC), 256, 0, stream>>>(ws0, geos, boxes, ws1);
  // layer 2: fused GEMM+sample (16 ch/block, in-LDS planes)
  fusedgs32_kernel<false><<<dim3(8, 8), 512, 0, stream>>>(
      lins + 16384, ws1, geos + 768, boxes + 768, ws0, nullptr, nullptr);
  // layer 3: fused GEMM+sample + mean-pool + dense head, feat straight to d_out
  fusedgs32_kernel<true><<<dim3(8, 8), 512, 0, stream>>>(
      lins + 32768, ws0, geos + 1536, boxes + 1536, feat, dw, out);
}

// Round 11
// 137.843 us; speedup vs baseline: 1.1164x; 1.1164x over previous
//
#include <hip/hip_runtime.h>

#define BB 8
#define CC 128

typedef _Float16 f16x4 __attribute__((ext_vector_type(4)));
typedef float f32x4 __attribute__((ext_vector_type(4)));
typedef __fp16 fp16x2 __attribute__((ext_vector_type(2)));

// Pack 2 f32 -> 2 f16 in one v_cvt_pkrtz_f16_f32.
__device__ __forceinline__ unsigned int pack2(float a, float b) {
  union { fp16x2 h; unsigned int u; } cv;
  cv.h = __builtin_amdgcn_cvt_pkrtz(a, b);
  return cv.u;
}

// Bilinear sample from a zero-border padded LDS plane.
// pl is [H+3][stride] with interior pixel (r,c) at pl[(r+1)*stride + (c+1)],
// border rows/cols are 0. Coords clamped to [-1, W]; out-of-range taps read 0.
__device__ __forceinline__ float sample_pad(const float* __restrict__ pl, int stride,
                                            float WF, float ix, float iy) {
  ix = fminf(fmaxf(ix, -1.0f), WF);
  iy = fminf(fmaxf(iy, -1.0f), WF);
  float x0f = floorf(ix), y0f = floorf(iy);
  float wx = ix - x0f, wy = iy - y0f;
  int xi = (int)x0f + 1, yi = (int)y0f + 1;
  const float* p0 = pl + yi * stride + xi;
  float v00 = p0[0], v01 = p0[1], v10 = p0[stride], v11 = p0[stride + 1];
  return (1.0f - wy) * ((1.0f - wx) * v00 + wx * v01) +
         wy * ((1.0f - wx) * v10 + wx * v11);
}

// Factorized box mask: validity of tap(i,j) = X_i * Y_j, so bilinear sum = mx*my.
__device__ __forceinline__ float box_mask(float bix, float biy, float WM1) {
  float bx0 = floorf(bix), by0 = floorf(biy);
  float bwx = bix - bx0, bwy = biy - by0;
  float mx = (((bx0 >= 0.0f) && (bx0 <= WM1)) ? (1.0f - bwx) : 0.0f) +
             (((bx0 >= -1.0f) && (bx0 <= WM1 - 1.0f)) ? bwx : 0.0f);
  float my = (((by0 >= 0.0f) && (by0 <= WM1)) ? (1.0f - bwy) : 0.0f) +
             (((by0 >= -1.0f) && (by0 <= WM1 - 1.0f)) ? bwy : 0.0f);
  return mx * my;
}

// ---------------- fused inLay: combine -> padded LDS + sample + box mask ----------
__global__ __launch_bounds__(256) void inlay_sample_kernel(
    const float* __restrict__ x, const float* __restrict__ lin,
    const float* __restrict__ geo, const float* __restrict__ box,
    const float* __restrict__ db, float* __restrict__ out,
    float* __restrict__ head) {
  const int H = 64, W = 64, HW = 4096;
  __shared__ float cp[67 * 68];
  int bc = blockIdx.x;
  int c = bc & (CC - 1);
  int b = bc >> 7;
  int tid = threadIdx.x;
  if (bc == 0 && tid < 80) head[tid] = db[tid % 10];  // bias init for atomic dense
  const float* xb = x + (size_t)b * 3 * HW;

  float w0 = lin[c * 3 + 0], w1 = lin[c * 3 + 1], w2 = lin[c * 3 + 2];

  if (tid < 68) {
    cp[tid] = 0.0f; cp[65 * 68 + tid] = 0.0f; cp[66 * 68 + tid] = 0.0f;
  } else if (tid < 132) {
    int r = tid - 67;
    cp[r * 68 + 0] = 0.0f; cp[r * 68 + 65] = 0.0f; cp[r * 68 + 66] = 0.0f;
  }

#pragma unroll
  for (int k = 0; k < 4; ++k) {
    int i4 = tid + k * 256;
    int base = i4 * 4;
    float4 f0 = *reinterpret_cast<const float4*>(&xb[base]);
    float4 f1 = *reinterpret_cast<const float4*>(&xb[HW + base]);
    float4 f2 = *reinterpret_cast<const float4*>(&xb[2 * HW + base]);
    int h = i4 >> 4, w = (i4 & 15) * 4;
    float* d = &cp[(h + 1) * 68 + w + 1];
    d[0] = w0 * f0.x + w1 * f1.x + w2 * f2.x;
    d[1] = w0 * f0.y + w1 * f1.y + w2 * f2.y;
    d[2] = w0 * f0.z + w1 * f1.z + w2 * f2.z;
    d[3] = w0 * f0.w + w1 * f1.w + w2 * f2.w;
  }
  __syncthreads();

  // Scaled affine coefficients: ix = 32*g0*xs + 32*g1*ys + (32*g2 + 31.5)
  const float* g = geo + c * 6;
  const float* bx = box + c * 6;
  float a0 = 32.0f * g[0], a1 = 32.0f * g[1], a2 = 32.0f * g[2] + 31.5f;
  float a3 = 32.0f * g[3], a4 = 32.0f * g[4], a5 = 32.0f * g[5] + 31.5f;
  float c0 = 32.0f * bx[0], c1 = 32.0f * bx[1], c2 = 32.0f * bx[2] + 31.5f;
  float c3 = 32.0f * bx[3], c4 = 32.0f * bx[4], c5 = 32.0f * bx[5] + 31.5f;
  float* o = out + ((size_t)b * CC + c) * HW;

#pragma unroll
  for (int k = 0; k < 16; ++k) {
    int px = tid + k * 256;
    int h = px >> 6, w = px & 63;
    float xs = (2.0f * w + 1.0f) / W - 1.0f;
    float ys = (2.0f * h + 1.0f) / H - 1.0f;
    float ix = fmaf(a0, xs, fmaf(a1, ys, a2));
    float iy = fmaf(a3, xs, fmaf(a4, ys, a5));
    float samp = sample_pad(cp, 68, 64.0f, ix, iy);
    float bix = fmaf(c0, xs, fmaf(c1, ys, c2));
    float biy = fmaf(c3, xs, fmaf(c4, ys, c5));
    o[px] = samp * box_mask(bix, biy, 63.0f);
  }
}

// ---------------- layer-0 GEMM via f16 MFMA: 64x64 tile, single-stage LDS ----------
// Layouts verified in rounds 6/7:
//   A frag: lane l holds A[row=l&15][k=16s+4*(l>>4)+j]   (f16x4, one ds_read_b64)
//   B frag: lane l holds B[k=16s+4*(l>>4)+j][col=l&15]
//   D:      lane l holds D[row=4*(l>>4)+i][col=l&15]
__global__ __launch_bounds__(256) void gemm64_mfma_kernel(
    const float* __restrict__ lin, const float* __restrict__ x,
    float* __restrict__ y) {
  const int Ci = 128, HW = 4096;
  __shared__ unsigned int A_lds[64 * 66];  // [row][kp] kp = k/2, stride 66 (pad)
  __shared__ unsigned int B_lds[64 * 66];  // [col][kp]
  int b = blockIdx.z;
  int row0 = blockIdx.y * 64, col0 = blockIdx.x * 64;
  const float* xb = x + (size_t)b * Ci * HW;
  float* yb = y + (size_t)b * CC * HW;
  int tid = threadIdx.x;

  // stage A: thread t -> row = t>>2, k-chunk (t&3)*32 (16 packed words)
  {
    int row = tid >> 2, kc = (tid & 3) * 32;
    const float* ap = &lin[(row0 + row) * Ci + kc];
    unsigned int* dst = &A_lds[row * 66 + (kc >> 1)];
#pragma unroll
    for (int i = 0; i < 8; ++i) {
      float4 v = *reinterpret_cast<const float4*>(ap + i * 4);
      dst[i * 2] = pack2(v.x, v.y);
      dst[i * 2 + 1] = pack2(v.z, v.w);
    }
  }
  // stage B (transpose): thread t -> kp = t>>2 (rows k=2kp,2kp+1), cols (t&3)*16..+16
  {
    int kp = tid >> 2, cg = (tid & 3) * 16;
    const float* b0p = &xb[(size_t)(2 * kp) * HW + col0 + cg];
    const float* b1p = &xb[(size_t)(2 * kp + 1) * HW + col0 + cg];
#pragma unroll
    for (int q = 0; q < 4; ++q) {
      float4 v0 = *reinterpret_cast<const float4*>(b0p + q * 4);
      float4 v1 = *reinterpret_cast<const float4*>(b1p + q * 4);
      unsigned int* bp_ = &B_lds[(cg + q * 4) * 66 + kp];
      bp_[0 * 66] = pack2(v0.x, v1.x);
      bp_[1 * 66] = pack2(v0.y, v1.y);
      bp_[2 * 66] = pack2(v0.z, v1.z);
      bp_[3 * 66] = pack2(v0.w, v1.w);
    }
  }
  __syncthreads();

  int w = tid >> 6, l = tid & 63;
  int lr = l & 15, lq = l >> 4;
  f32x4 acc0 = {0.f, 0.f, 0.f, 0.f};
  f32x4 acc1 = acc0, acc2 = acc0, acc3 = acc0;
  const unsigned int* arow = &A_lds[(w * 16 + lr) * 66 + 2 * lq];
  const unsigned int* bcol = &B_lds[lr * 66 + 2 * lq];
#pragma unroll
  for (int s = 0; s < 8; ++s) {
    f16x4 af = *reinterpret_cast<const f16x4*>(arow + s * 8);
    f16x4 b0 = *reinterpret_cast<const f16x4*>(bcol + 0 * 16 * 66 + s * 8);
    f16x4 b1 = *reinterpret_cast<const f16x4*>(bcol + 1 * 16 * 66 + s * 8);
    f16x4 b2 = *reinterpret_cast<const f16x4*>(bcol + 2 * 16 * 66 + s * 8);
    f16x4 b3 = *reinterpret_cast<const f16x4*>(bcol + 3 * 16 * 66 + s * 8);
    acc0 = __builtin_amdgcn_mfma_f32_16x16x16f16(af, b0, acc0, 0, 0, 0);
    acc1 = __builtin_amdgcn_mfma_f32_16x16x16f16(af, b1, acc1, 0, 0, 0);
    acc2 = __builtin_amdgcn_mfma_f32_16x16x16f16(af, b2, acc2, 0, 0, 0);
    acc3 = __builtin_amdgcn_mfma_f32_16x16x16f16(af, b3, acc3, 0, 0, 0);
  }
#pragma unroll
  for (int i = 0; i < 4; ++i) {
    float* yr = yb + (size_t)(row0 + w * 16 + lq * 4 + i) * HW + col0 + lr;
    yr[0]  = acc0[i];
    yr[16] = acc1[i];
    yr[32] = acc2[i];
    yr[48] = acc3[i];
  }
}

// ---------------- 32x32-layer GEMM via f16 MFMA: M=32ch x N=64px, K=128 ----------
// Same fragment layouts/pack scheme as gemm64_mfma (verified). One barrier.
// Wave w: row strip (w&1)*16, col tiles (w>>1)*2 + {0,1}.
__global__ __launch_bounds__(256) void gemm32_mfma_kernel(
    const float* __restrict__ lin, const float* __restrict__ x,
    float* __restrict__ y) {
  const int Ci = 128, HW = 1024;
  __shared__ unsigned int A_lds[32 * 66];  // [row(ch)][kp]
  __shared__ unsigned int B_lds[64 * 66];  // [col(px)][kp]
  int b = blockIdx.z;
  int row0 = blockIdx.y * 32, col0 = blockIdx.x * 64;
  const float* xb = x + (size_t)b * Ci * HW;
  float* yb = y + (size_t)b * CC * HW;
  int tid = threadIdx.x;

  // stage A: thread t -> row = t>>3 (0..31), k-chunk (t&7)*16 (8 packed words)
  {
    int row = tid >> 3, kc = (tid & 7) * 16;
    const float* ap = &lin[(row0 + row) * Ci + kc];
    unsigned int* dst = &A_lds[row * 66 + (kc >> 1)];
#pragma unroll
    for (int i = 0; i < 4; ++i) {
      float4 v = *reinterpret_cast<const float4*>(ap + i * 4);
      dst[i * 2] = pack2(v.x, v.y);
      dst[i * 2 + 1] = pack2(v.z, v.w);
    }
  }
  // stage B (transpose): thread t -> kp = t>>2 (0..63), cols (t&3)*16..+16
  {
    int kp = tid >> 2, cg = (tid & 3) * 16;
    const float* b0p = &xb[(size_t)(2 * kp) * HW + col0 + cg];
    const float* b1p = &xb[(size_t)(2 * kp + 1) * HW + col0 + cg];
#pragma unroll
    for (int q = 0; q < 4; ++q) {
      float4 v0 = *reinterpret_cast<const float4*>(b0p + q * 4);
      float4 v1 = *reinterpret_cast<const float4*>(b1p + q * 4);
      unsigned int* bp_ = &B_lds[(cg + q * 4) * 66 + kp];
      bp_[0 * 66] = pack2(v0.x, v1.x);
      bp_[1 * 66] = pack2(v0.y, v1.y);
      bp_[2 * 66] = pack2(v0.z, v1.z);
      bp_[3 * 66] = pack2(v0.w, v1.w);
    }
  }
  __syncthreads();

  int w = tid >> 6, l = tid & 63;
  int lr = l & 15, lq = l >> 4;
  int rs = (w & 1) * 16;       // row strip within 32 channels
  int ct0 = (w >> 1) * 2;      // first of two 16-col tiles
  f32x4 acc0 = {0.f, 0.f, 0.f, 0.f};
  f32x4 acc1 = acc0;
  const unsigned int* arow = &A_lds[(rs + lr) * 66 + 2 * lq];
  const unsigned int* bc0 = &B_lds[(ct0 * 16 + lr) * 66 + 2 * lq];
  const unsigned int* bc1 = &B_lds[((ct0 + 1) * 16 + lr) * 66 + 2 * lq];
#pragma unroll
  for (int s = 0; s < 8; ++s) {
    f16x4 af = *reinterpret_cast<const f16x4*>(arow + s * 8);
    f16x4 b0 = *reinterpret_cast<const f16x4*>(bc0 + s * 8);
    f16x4 b1 = *reinterpret_cast<const f16x4*>(bc1 + s * 8);
    acc0 = __builtin_amdgcn_mfma_f32_16x16x16f16(af, b0, acc0, 0, 0, 0);
    acc1 = __builtin_amdgcn_mfma_f32_16x16x16f16(af, b1, acc1, 0, 0, 0);
  }
#pragma unroll
  for (int i = 0; i < 4; ++i) {
    float* yr = yb + (size_t)(row0 + rs + lq * 4 + i) * HW + col0 + ct0 * 16 + lr;
    yr[0]  = acc0[i];
    yr[16] = acc1[i];
  }
}

// ---------------- fused sample(64x64) + MaxPool2d_G -> 32x32, 256 threads ---------
__global__ __launch_bounds__(256) void sampmax_kernel(
    const float* __restrict__ y, const float* __restrict__ geo,
    const float* __restrict__ box, float* __restrict__ out) {
  __shared__ __align__(16) float sp[64 * 68];     // sampled plane
  __shared__ __align__(16) float arena[67 * 68];  // pl padded (ph0-1) then cb (ph2-3)
  __shared__ float wv[4];
  __shared__ int wi[4];
  __shared__ int am_s;
  float* pl = arena;
  float* cb = arena;

  int bc = blockIdx.x;
  int c = bc & (CC - 1);
  int tid = threadIdx.x;

  if (tid < 68) {
    pl[tid] = 0.0f; pl[65 * 68 + tid] = 0.0f; pl[66 * 68 + tid] = 0.0f;
  } else if (tid < 132) {
    int r = tid - 67;
    pl[r * 68 + 0] = 0.0f; pl[r * 68 + 65] = 0.0f; pl[r * 68 + 66] = 0.0f;
  }
  {
    const float* plane = y + (size_t)bc * 4096;
#pragma unroll
    for (int k = 0; k < 4; ++k) {
      int i4 = tid + k * 256;
      float4 f = *reinterpret_cast<const float4*>(&plane[i4 * 4]);
      int h = i4 >> 4, w = (i4 & 15) * 4;
      float* d = &pl[(h + 1) * 68 + w + 1];
      d[0] = f.x; d[1] = f.y; d[2] = f.z; d[3] = f.w;
    }
  }
  __syncthreads();

  {
    const float* g = geo + c * 6;
    const float* bx = box + c * 6;
    float a0 = 32.0f * g[0], a1 = 32.0f * g[1], a2 = 32.0f * g[2] + 31.5f;
    float a3 = 32.0f * g[3], a4 = 32.0f * g[4], a5 = 32.0f * g[5] + 31.5f;
    float c0 = 32.0f * bx[0], c1 = 32.0f * bx[1], c2 = 32.0f * bx[2] + 31.5f;
    float c3 = 32.0f * bx[3], c4 = 32.0f * bx[4], c5 = 32.0f * bx[5] + 31.5f;
#pragma unroll
    for (int k = 0; k < 16; ++k) {
      int px = tid + k * 256;
      int h = px >> 6, w = px & 63;
      float xs = (2.0f * w + 1.0f) / 64.0f - 1.0f;
      float ys = (2.0f * h + 1.0f) / 64.0f - 1.0f;
      float ix = fmaf(a0, xs, fmaf(a1, ys, a2));
      float iy = fmaf(a3, xs, fmaf(a4, ys, a5));
      float samp = sample_pad(pl, 68, 64.0f, ix, iy);
      float bix = fmaf(c0, xs, fmaf(c1, ys, c2));
      float biy = fmaf(c3, xs, fmaf(c4, ys, c5));
      sp[h * 68 + w] = samp * box_mask(bix, biy, 63.0f);
    }
  }
  __syncthreads();

  // Phase 2: vertical 32-row sliding box sums -> cb
  {
    int strip = tid >> 4, w4 = (tid & 15) * 4;
    int h0 = strip * 4;
    float4 a = make_float4(0.f, 0.f, 0.f, 0.f);
    float4 keep0 = a, keep1 = a, keep2 = a;
#pragma unroll
    for (int j = 0; j < 32; ++j) {
      int r = h0 + j - 16;
      bool valid = (r >= 0) && (r < 64);
      int rc = valid ? r : 0;
      float4 f = *reinterpret_cast<const float4*>(&sp[rc * 68 + w4]);
      f.x = valid ? f.x : 0.0f; f.y = valid ? f.y : 0.0f;
      f.z = valid ? f.z : 0.0f; f.w = valid ? f.w : 0.0f;
      if (j == 0) keep0 = f;
      if (j == 1) keep1 = f;
      if (j == 2) keep2 = f;
      a.x += f.x; a.y += f.y; a.z += f.z; a.w += f.w;
    }
    *reinterpret_cast<float4*>(&cb[(h0 + 0) * 68 + w4]) = a;
#pragma unroll
    for (int j = 32; j < 35; ++j) {
      int r = h0 + j - 16;
      bool valid = (r < 64);
      int rc = valid ? r : 0;
      float4 f = *reinterpret_cast<const float4*>(&sp[rc * 68 + w4]);
      f.x = valid ? f.x : 0.0f; f.y = valid ? f.y : 0.0f;
      f.z = valid ? f.z : 0.0f; f.w = valid ? f.w : 0.0f;
      float4 kp = (j == 32) ? keep0 : ((j == 33) ? keep1 : keep2);
      a.x += f.x - kp.x; a.y += f.y - kp.y; a.z += f.z - kp.z; a.w += f.w - kp.w;
      *reinterpret_cast<float4*>(&cb[(h0 + j - 31) * 68 + w4]) = a;
    }
  }
  __syncthreads();

  // Phase 3: horizontal 32-col sliding box sums + argmax
  float best = -3.402823466e+38f;
  int bidx = 0x7fffffff;
#pragma unroll
  for (int hh = 0; hh < 4; ++hh) {
    int h = (tid >> 4) + hh * 16;
    int w4 = (tid & 15) * 4;
    float s0 = 0.f, k0 = 0.f, k1 = 0.f, k2 = 0.f;
#pragma unroll
    for (int q = 0; q < 8; ++q) {
      int u0 = w4 - 16 + 4 * q;
      bool ok = (u0 >= 0) && (u0 <= 60);
      int uc = ok ? u0 : 0;
      float4 f = *reinterpret_cast<const float4*>(&cb[h * 68 + uc]);
      f.x = ok ? f.x : 0.0f; f.y = ok ? f.y : 0.0f;
      f.z = ok ? f.z : 0.0f; f.w = ok ? f.w : 0.0f;
      if (q == 0) { k0 = f.x; k1 = f.y; k2 = f.z; }
      s0 += f.x; s0 += f.y; s0 += f.z; s0 += f.w;
    }
    float ftx = 0.f, fty = 0.f, ftz = 0.f;
    {
      int u0 = w4 + 16;
      bool ok = (u0 <= 60);
      int uc = ok ? u0 : 0;
      float4 f = *reinterpret_cast<const float4*>(&cb[h * 68 + uc]);
      ftx = ok ? f.x : 0.0f; fty = ok ? f.y : 0.0f; ftz = ok ? f.z : 0.0f;
    }
    float s1 = s0 - k0 + ftx;
    float s2 = s1 - k1 + fty;
    float s3 = s2 - k2 + ftz;
    float sv[4] = {s0, s1, s2, s3};
#pragma unroll
    for (int d = 0; d < 4; ++d) {
      int i = (h << 6) + w4 + d;
      if (sv[d] > best) { best = sv[d]; bidx = i; }
    }
  }
#pragma unroll
  for (int off = 32; off > 0; off >>= 1) {
    float v2 = __shfl_down(best, off);
    int i2 = __shfl_down(bidx, off);
    if (v2 > best || (v2 == best && i2 < bidx)) { best = v2; bidx = i2; }
  }
  if ((tid & 63) == 0) { wv[tid >> 6] = best; wi[tid >> 6] = bidx; }
  __syncthreads();
  if (tid == 0) {
    float bv = wv[0]; int bi = wi[0];
#pragma unroll
    for (int k = 1; k < 4; ++k)
      if (wv[k] > bv || (wv[k] == bv && wi[k] < bi)) { bv = wv[k]; bi = wi[k]; }
    am_s = bi;
  }
  __syncthreads();

  int am = am_s;
  int r = am >> 6, cx = am & 63;
  float* o = out + (size_t)bc * 1024;
#pragma unroll
  for (int k = 0; k < 4; ++k) {
    int idx = tid + k * 256;
    int oi = idx >> 5, oj = idx & 31;
    int rr = r + oi - 16, cj = cx + oj - 16;
    bool v = (rr >= 0) && (rr < 64) && (cj >= 0) && (cj < 64);
    int rrc = v ? rr : 0, cjc = v ? cj : 0;
    o[idx] = v ? sp[rrc * 68 + cjc] : 0.0f;
  }
}

// ---------------- 32x32 sample (+optional mean-pool + dense-head atomics) --------
template <bool POOL>
__global__ __launch_bounds__(256) void sample32_kernel(
    const float* __restrict__ y, const float* __restrict__ geo,
    const float* __restrict__ box, float* __restrict__ out,
    const float* __restrict__ dw, float* __restrict__ head) {
  const int W = 32, HW = 1024;
  __shared__ float pl[35 * 36];
  __shared__ float wred[4];
  int bc = blockIdx.x;
  int c = bc & (CC - 1);
  int b = bc >> 7;
  int tid = threadIdx.x;

  if (tid < 36) {
    pl[tid] = 0.0f; pl[33 * 36 + tid] = 0.0f; pl[34 * 36 + tid] = 0.0f;
  } else if (tid < 68) {
    int r = tid - 35;
    pl[r * 36 + 0] = 0.0f; pl[r * 36 + 33] = 0.0f; pl[r * 36 + 34] = 0.0f; pl[r * 36 + 35] = 0.0f;
  }
  {
    const float* plane = y + (size_t)bc * HW;
    float4 f = *reinterpret_cast<const float4*>(&plane[tid * 4]);
    int h = tid >> 3, w = (tid & 7) * 4;
    float* d = &pl[(h + 1) * 36 + w + 1];
    d[0] = f.x; d[1] = f.y; d[2] = f.z; d[3] = f.w;
  }
  __syncthreads();

  // ix = 16*g0*xs + 16*g1*ys + (16*g2 + 15.5)
  const float* g = geo + c * 6;
  const float* bxp = box + c * 6;
  float a0 = 16.0f * g[0], a1 = 16.0f * g[1], a2 = 16.0f * g[2] + 15.5f;
  float a3 = 16.0f * g[3], a4 = 16.0f * g[4], a5 = 16.0f * g[5] + 15.5f;
  float c0 = 16.0f * bxp[0], c1 = 16.0f * bxp[1], c2 = 16.0f * bxp[2] + 15.5f;
  float c3 = 16.0f * bxp[3], c4 = 16.0f * bxp[4], c5 = 16.0f * bxp[5] + 15.5f;
  float* o = out + (size_t)bc * HW;
  float psum = 0.f;
#pragma unroll
  for (int k = 0; k < 4; ++k) {
    int px = tid + k * 256;
    int h = px >> 5, w = px & 31;
    float xs = (2.0f * w + 1.0f) / W - 1.0f;
    float ys = (2.0f * h + 1.0f) / W - 1.0f;
    float ix = fmaf(a0, xs, fmaf(a1, ys, a2));
    float iy = fmaf(a3, xs, fmaf(a4, ys, a5));
    float samp = sample_pad(pl, 36, 32.0f, ix, iy);
    float bix = fmaf(c0, xs, fmaf(c1, ys, c2));
    float biy = fmaf(c3, xs, fmaf(c4, ys, c5));
    float res = samp * box_mask(bix, biy, 31.0f);
    o[px] = res;
    if (POOL) psum += res;
  }
  if (POOL) {
    int lane = tid & 63, wid = tid >> 6;  // 4 waves
    float r = psum;
#pragma unroll
    for (int off = 32; off > 0; off >>= 1) r += __shfl_down(r, off);
    if (lane == 0) wred[wid] = r;
    __syncthreads();
    if (tid < 10) {
      float t = (wred[0] + wred[1] + wred[2] + wred[3]) * (1.0f / 1024.0f);
      atomicAdd(&head[b * 10 + tid], t * dw[tid * 128 + c]);
    }
  }
}

extern "C" void kernel_launch(void* const* d_in, const int* in_sizes, int n_in,
                              void* d_out, int out_size, void* d_ws, size_t ws_size,
                              hipStream_t stream) {
  const float* x     = (const float*)d_in[0];   // [8,3,64,64]
  const float* geo0  = (const float*)d_in[1];   // [128,2,3]
  const float* lin0  = (const float*)d_in[2];   // [128,3]
  const float* box0  = (const float*)d_in[3];   // [128,2,3]
  const float* geos  = (const float*)d_in[4];   // [3,128,2,3]
  const float* lins  = (const float*)d_in[5];   // [3,128,128]
  const float* boxes = (const float*)d_in[6];   // [3,128,2,3]
  const float* dw    = (const float*)d_in[7];   // [10,128]
  const float* db    = (const float*)d_in[8];   // [10]

  float* out  = (float*)d_out;      // [8,10] then feat [8,128,32,32]
  float* feat = out + 80;
  float* ws   = (float*)d_ws;
  float* ws0  = ws;                 // 16 MB regions
  float* ws1  = ws + 4194304;
  float* ws2  = ws + 8388608;

  // inLay: fused combine(Ci=3) + sample -> ws1; also writes head bias
  inlay_sample_kernel<<<dim3(BB * CC), 256, 0, stream>>>(x, lin0, geo0, box0, db, ws1, out);
  // layer 0: f16-MFMA GEMM (64x64 tiles) -> fused sample+maxpool -> 32x32
  gemm64_mfma_kernel<<<dim3(64, 2, BB), 256, 0, stream>>>(lins, ws1, ws0);
  sampmax_kernel<<<dim3(BB * CC), 256, 0, stream>>>(ws0, geos, boxes, ws1);
  // layer 2: f16-MFMA GEMM then sample
  gemm32_mfma_kernel<<<dim3(16, 4, BB), 256, 0, stream>>>(lins + 16384, ws1, ws2);
  sample32_kernel<false><<<dim3(BB * CC), 256, 0, stream>>>(ws2, geos + 768, boxes + 768, ws0, nullptr, nullptr);
  // layer 3: f16-MFMA GEMM then sample + mean-pool + dense head
  gemm32_mfma_kernel<<<dim3(16, 4, BB), 256, 0, stream>>>(lins + 32768, ws0, ws2);
  sample32_kernel<true><<<dim3(BB * CC), 256, 0, stream>>>(ws2, geos + 1536, boxes + 1536, feat, dw, out);
}